// Round 6
// baseline (1717.080 us; speedup 1.0000x reference)
//
#include <hip/hip_runtime.h>
#include <math.h>

#define NS 1024
#define NA 2048
#define CIN 16
#define CC 32
#define LL 150
#define LC 75

typedef __attribute__((ext_vector_type(8))) short short8;
typedef __attribute__((ext_vector_type(4))) float float4v;

__device__ __forceinline__ unsigned short f2bf(float f) {
  // round-to-nearest-even fp32 -> bf16
  unsigned int u = __float_as_uint(f);
  unsigned int r = (u + 0x7FFFu + ((u >> 16) & 1u)) >> 16;
  return (unsigned short)r;
}

// ---------------------------------------------------------------------------
// K1 v2: conv1d(k=5,pad=2) + ReLU + sum over 16 reads, bf16 MFMA implicit GEMM.
// vs v1: (1) double-buffered LDS staging — stage r+1 is issued BEFORE the MFMA
// of stage r, one barrier per stage (was 2): global-load latency hides under
// MFMA/staging of co-resident waves. (2) f2bf pairs via v_cvt_pk_bf16_f32
// (1 instr for 2 converts, same RNE rounding as f2bf).
// LDS 2 x 9856 B. 8 blocks/CU (wave-limited), 256 threads.
// ---------------------------------------------------------------------------
__global__ __launch_bounds__(256) void k_conv_sum_mfma(const float* __restrict__ x,
                                                       const float* __restrict__ w,
                                                       float* __restrict__ red) {
  __shared__ unsigned short xs[2][154 * 32];   // 2 x 616 slots of 16B
  const int a = blockIdx.x;
  const int tid = threadIdx.x;
  const int lane = tid & 63;
  const int wv = tid >> 6;

  // A-fragments (weights) -> registers. lane holds A[m=lane&15][k=8*(lane>>4)+j]
  short8 afr[2][3];
  {
    const int mrow = lane & 15;
    const int h = lane >> 4;
    for (int mt = 0; mt < 2; ++mt) {
      const int c = mt * 16 + mrow;
      for (int s = 0; s < 3; ++s) {
        short8 f;
#pragma unroll
        for (int j = 0; j < 8; ++j) {
          int ic = 4 * h + (j >> 1);
          int tap = 2 * s + (j & 1);
          float wval = (tap < 5) ? w[c * 80 + ic * 5 + tap] : 0.f;
          f[j] = (short)f2bf(wval);
        }
        afr[mt][s] = f;
      }
    }
  }

  float4v sum[2][3];
#pragma unroll
  for (int mt = 0; mt < 2; ++mt)
#pragma unroll
    for (int nt = 0; nt < 3; ++nt) sum[mt][nt] = (float4v)(0.f);

  const int nbase = wv * 48;
  const int nrow = lane & 15;
  const int hh = lane >> 4;
  const float4v zf = (float4v)(0.f);

  // stage read r into buffer buf (all 616 slots fully written incl. pad rows)
  auto stage = [&](int r, int buf) {
    const float* xr = x + (size_t)(a * 16 + r) * (CIN * LL);
    for (int s = tid; s < 616; s += 256) {
      const int p = s >> 2;
      const int h4 = (s & 3) * 4;                  // ic base for this slot
      const float* xb = xr + h4 * LL + p;
      const bool qe_ok = (p >= 2) && (p <= 151);   // px[p]   = x[p-2]
      const bool qo_ok = (p >= 1) && (p <= 150);   // px[p+1] = x[p-1]
      unsigned int dw[4];
#pragma unroll
      for (int c = 0; c < 4; ++c) {
        float ve = qe_ok ? xb[c * LL - 2] : 0.f;
        float vo = qo_ok ? xb[c * LL - 1] : 0.f;
        unsigned int pk;
        asm("v_cvt_pk_bf16_f32 %0, %1, %2" : "=v"(pk) : "v"(ve), "v"(vo));
        dw[c] = pk;                                // low16=bf(ve), high16=bf(vo)
      }
      *(uint4*)&xs[buf][s * 8] = make_uint4(dw[0], dw[1], dw[2], dw[3]);
    }
  };

  stage(0, 0);
  __syncthreads();

  for (int r = 0; r < 16; ++r) {
    const int cur = r & 1;
    if (r + 1 < 16) stage(r + 1, cur ^ 1);   // buf cur^1 last read at stage r-1 (pre-barrier) — safe

    float4v acc[2][3];
#pragma unroll
    for (int s = 0; s < 3; ++s) {
#pragma unroll
      for (int nt = 0; nt < 3; ++nt) {
        int p = nbase + nt * 16 + nrow + 2 * s;
        if (p >= 154) p -= 154;                    // only for discarded cols
        short8 bfrag = *(const short8*)&xs[cur][(4 * p + hh) * 8];
#pragma unroll
        for (int mt = 0; mt < 2; ++mt) {
          acc[mt][nt] = __builtin_amdgcn_mfma_f32_16x16x32_bf16(
              afr[mt][s], bfrag, (s == 0) ? zf : acc[mt][nt], 0, 0, 0);
        }
      }
    }
#pragma unroll
    for (int mt = 0; mt < 2; ++mt)
#pragma unroll
      for (int nt = 0; nt < 3; ++nt)
#pragma unroll
        for (int q = 0; q < 4; ++q) sum[mt][nt][q] += fmaxf(acc[mt][nt][q], 0.f);

    __syncthreads();   // staging of r+1 done AND MFMA reads of r done
  }

  // C/D layout (16x16): col = lane&15 -> l, row = (lane>>4)*4+reg -> c
  const int ccol = lane & 15;
  const int crow4 = (lane >> 4) * 4;
  for (int mt = 0; mt < 2; ++mt)
    for (int nt = 0; nt < 3; ++nt) {
      int l = nbase + nt * 16 + ccol;
      if (l < LL) {
#pragma unroll
        for (int q = 0; q < 4; ++q) {
          int c = mt * 16 + crow4 + q;
          red[(size_t)a * (CC * LL) + c * LL + l] = sum[mt][nt][q];
        }
      }
    }
}

// ---------------------------------------------------------------------------
// K2: red2 = relu(comb_w @ [red0|red1]) in place over red0 (unchanged)
// ---------------------------------------------------------------------------
__global__ __launch_bounds__(256) void k_comb(const float* __restrict__ red0,
                                              const float* __restrict__ red1,
                                              const float* __restrict__ cw,
                                              float* __restrict__ out) {
  __shared__ float ins[64][152];
  __shared__ float cwl[64][CC];
  const int a = blockIdx.x;
  const int tid = threadIdx.x;

  for (int i = tid; i < 64 * CC; i += 256) {
    int c = i & 31; int c2 = i >> 5;
    cwl[c2][c] = cw[c * 64 + c2];
  }
  for (int i = tid; i < CC * LL; i += 256) {
    int c2 = i / LL; int l = i - c2 * LL;
    ins[c2][l] = red0[(size_t)a * (CC * LL) + i];
    ins[32 + c2][l] = red1[(size_t)a * (CC * LL) + i];
  }
  __syncthreads();

  const int c = tid & 31;
  const int lg = tid >> 5;
  const int l0 = lg * 19;
  const int nl = (LL - l0 < 19) ? (LL - l0) : 19;
  float v[19];
#pragma unroll
  for (int j = 0; j < 19; ++j) v[j] = 0.f;
  for (int c2 = 0; c2 < 64; ++c2) {
    float wv = cwl[c2][c];
#pragma unroll
    for (int j = 0; j < 19; ++j) v[j] += wv * ins[c2][l0 + j];
  }
  float* o = out + (size_t)a * (CC * LL) + c * LL + l0;
  for (int j = 0; j < nl; ++j) o[j] = fmaxf(v[j], 0.f);
}

// ---------------------------------------------------------------------------
// K3 v2: per-SITE fused compressor. Conv is linear, so with pre-relu
// accumulators v0 (allele0) and v1 (allele1):
//   cfa0 = relu(v0), cfa1 = relu(v1), cfs = relu(v0+v1).
// One read of the red pair, one weight pass, 3 outputs -> replaces the old
// {NA allele-mode + NS site-mode} launch pair. LDS 54.3 KB -> 3 blocks/CU.
// ---------------------------------------------------------------------------
__global__ __launch_bounds__(256) void k_compress2(const float* __restrict__ src,
                                                   const float* __restrict__ w,
                                                   float* __restrict__ cfa,
                                                   float* __restrict__ cfs) {
  __shared__ float ins0[CC][164];
  __shared__ float ins1[CC][164];
  __shared__ float ws[CC][3][CC];
  const int sfull = blockIdx.x;
  const int tid = threadIdx.x;

  for (int i = tid; i < CC * 3 * CC; i += 256) {
    int c = i & 31; int kk = i >> 5; int ic = kk / 3; int t = kk - ic * 3;
    ws[ic][t][c] = w[c * (CC * 3) + ic * 3 + t];
  }
  if (tid < CC) {
    ins0[tid][0] = 0.f; ins0[tid][1] = 0.f; ins0[tid][152] = 0.f; ins0[tid][153] = 0.f;
    ins1[tid][0] = 0.f; ins1[tid][1] = 0.f; ins1[tid][152] = 0.f; ins1[tid][153] = 0.f;
  }
  {
    const float* s0 = src + (size_t)(2 * sfull) * (CC * LL);
    const float* s1 = s0 + CC * LL;
    for (int i = tid; i < CC * LL; i += 256) {
      int ic = i / LL; int l = i - ic * LL;
      ins0[ic][l + 2] = s0[i];
      ins1[ic][l + 2] = s1[i];
    }
  }
  __syncthreads();

  const int c = tid & 31;
  const int jg = tid >> 5;
  const int j0 = jg * 10;
  const int nj = (LC - j0 < 10) ? (LC - j0) : 10;
  float v0[10], v1[10];
#pragma unroll
  for (int j = 0; j < 10; ++j) { v0[j] = 0.f; v1[j] = 0.f; }
  for (int ic = 0; ic < CC; ++ic) {
    float w0 = ws[ic][0][c], w1 = ws[ic][1][c], w2 = ws[ic][2][c];
    float xa[12], xb[12];
#pragma unroll
    for (int i = 0; i < 12; ++i) {
      xa[i] = ins0[ic][2 * j0 + 2 * i];
      xb[i] = ins1[ic][2 * j0 + 2 * i];
    }
#pragma unroll
    for (int j = 0; j < 10; ++j) {
      v0[j] += w0 * xa[j] + w1 * xa[j + 1] + w2 * xa[j + 2];
      v1[j] += w0 * xb[j] + w1 * xb[j + 1] + w2 * xb[j + 2];
    }
  }
  float* oa0 = cfa + (size_t)(2 * sfull) * (CC * LC) + c * LC + j0;
  float* oa1 = oa0 + CC * LC;
  float* os  = cfs + (size_t)sfull * (CC * LC) + c * LC + j0;
  for (int j = 0; j < nj; ++j) {
    float a0 = v0[j], a1 = v1[j];
    oa0[j] = fmaxf(a0, 0.f);
    oa1[j] = fmaxf(a1, 0.f);
    os[j]  = fmaxf(a0 + a1, 0.f);
  }
}

// ---------------------------------------------------------------------------
// K4 v5: per-ALLELE fused cross-attention, spill-free (unchanged from round 5)
// ---------------------------------------------------------------------------
#define BKV   0
#define BW    4800
#define BQT   8064
#define BCF   10464
#define BKB   10464
#define BVB   15328
#define BROWP 0
#define BPART 6080
#define BMS   6336
#define ARENA 20320

__global__ __launch_bounds__(256) void k_attn(const float* __restrict__ cfa,
                                              const float* __restrict__ cfs0,
                                              const float* __restrict__ wq,
                                              const float* __restrict__ wk,
                                              const float* __restrict__ wv,
                                              const float* __restrict__ wo,
                                              float* __restrict__ eout) {
  __shared__ float ar[ARENA];
  const int a = blockIdx.x;
  const int s = a >> 1;
  const int tid = threadIdx.x;
  const int g = tid >> 5;
  const int t = tid & 31;

  // ---- phase A: stage weights (in-major, stride 33), kv, cf ----
  for (int i = tid; i < CC * CC; i += 256) {
    int o = i >> 5, ii = i & 31;
    ar[BW + ii * 33 + o]        = wq[i];
    ar[BW + 1056 + ii * 33 + o] = wk[i];
    ar[BW + 2112 + ii * 33 + o] = wv[i];
  }
  {
    const float* sg = cfs0 + (size_t)s * (CC * LC);
    const float* a0 = cfa + (size_t)(2 * s) * (CC * LC);
    const float* a1 = a0 + CC * LC;
    const int sel = a & 1;
    for (int i = tid; i < CC * LC; i += 256) {
      int c = i / 75, l = i - c * 75;
      float v0 = a0[i], v1 = a1[i];
      ar[BKV + c * 150 + l]      = sg[i];
      ar[BKV + c * 150 + 75 + l] = v0 + v1;
      ar[BCF + c * 77 + l]       = sel ? v1 : v0;
    }
  }
  __syncthreads();

  // ---- phase B1: q -> QT (LDS), cf partial column-sum ----
  float cfp = 0.f;
  {
    float wqc[32];
#pragma unroll
    for (int ii = 0; ii < 32; ++ii) wqc[ii] = ar[BW + ii * 33 + t];
    for (int row = g; row < 75; row += 8) {
      float acc = 0.f;
#pragma unroll
      for (int ii = 0; ii < 32; ++ii) acc += wqc[ii] * ar[BCF + ii * 77 + row];
      ar[BQT + row * 32 + t] = acc;
      cfp += ar[BCF + t * 77 + row];
    }
  }
  __syncthreads();   // QT visible; CF reads done -> KB may overwrite

  // ---- phase B2: k,v projection -> KB (over CF), VB ----
  {
    float wkc[32], wvc[32];
#pragma unroll
    for (int ii = 0; ii < 32; ++ii) {
      wkc[ii] = ar[BW + 1056 + ii * 33 + t];
      wvc[ii] = ar[BW + 2112 + ii * 33 + t];
    }
    for (int idx = tid; idx < CC * LL; idx += 256) {
      int o = idx & 31, m = idx >> 5;
      float ka = 0.f, va = 0.f;
#pragma unroll
      for (int ii = 0; ii < 32; ++ii) {
        float x = ar[BKV + ii * 150 + m];
        ka += wkc[ii] * x;
        va += wvc[ii] * x;
      }
      ar[BKB + o * 152 + m] = ka;
      ar[BVB + o * 156 + m] = va;
    }
    if (tid < 64) ar[BVB + (tid >> 1) * 156 + 150 + (tid & 1)] = 0.f;  // PV pad
  }
  __syncthreads();   // KB/VB ready; KV+W dead -> ROWP may overwrite

  // ---- phase D: per-chunk (5 rows) scores -> softmax -> PV ----
  float ms = 0.f;
  const int rbase = BROWP + g * 760;
  const float scale = 0.17677669529663687f;   // 1/sqrt(32)
#pragma unroll 1
  for (int cc = 0; cc < 2; ++cc) {
    const int ch = g + 8 * cc;
    if (ch >= 15) break;
    const int r0 = ch * 5;

    float2 acc[5][3];
#pragma unroll
    for (int i = 0; i < 5; ++i)
#pragma unroll
      for (int u = 0; u < 3; ++u) acc[i][u] = make_float2(0.f, 0.f);

#pragma unroll 1
    for (int c2 = 0; c2 < 32; c2 += 2) {
      float2 q01[5];
#pragma unroll
      for (int i = 0; i < 5; ++i) q01[i] = *(const float2*)&ar[BQT + (r0 + i) * 32 + c2];
      const int cb0 = BKB + c2 * 152 + 2 * t;
      const int cb1 = cb0 + 152;
      float2 ka0 = *(const float2*)&ar[cb0];
      float2 ka1 = *(const float2*)&ar[cb0 + 64];
      float2 ka2 = *(const float2*)&ar[cb0 + 128];
      float2 kb0 = *(const float2*)&ar[cb1];
      float2 kb1 = *(const float2*)&ar[cb1 + 64];
      float2 kb2 = *(const float2*)&ar[cb1 + 128];
#pragma unroll
      for (int i = 0; i < 5; ++i) {
        acc[i][0].x += q01[i].x * ka0.x + q01[i].y * kb0.x;
        acc[i][0].y += q01[i].x * ka0.y + q01[i].y * kb0.y;
        acc[i][1].x += q01[i].x * ka1.x + q01[i].y * kb1.x;
        acc[i][1].y += q01[i].x * ka1.y + q01[i].y * kb1.y;
        acc[i][2].x += q01[i].x * ka2.x + q01[i].y * kb2.x;
        acc[i][2].y += q01[i].x * ka2.y + q01[i].y * kb2.y;
      }
    }

    float inv[5];
#pragma unroll
    for (int i = 0; i < 5; ++i) {
      float s0x = acc[i][0].x * scale, s0y = acc[i][0].y * scale;
      float s1x = acc[i][1].x * scale, s1y = acc[i][1].y * scale;
      float s2x = acc[i][2].x * scale, s2y = acc[i][2].y * scale;
      if (t >= 11) { s2x = -1e30f; s2y = -1e30f; }   // m=128+2t >= 150
      float mx = fmaxf(fmaxf(fmaxf(s0x, s0y), fmaxf(s1x, s1y)), fmaxf(s2x, s2y));
#pragma unroll
      for (int off = 16; off > 0; off >>= 1) mx = fmaxf(mx, __shfl_xor(mx, off, 32));
      float p0x = __expf(s0x - mx), p0y = __expf(s0y - mx);
      float p1x = __expf(s1x - mx), p1y = __expf(s1y - mx);
      float p2x = __expf(s2x - mx), p2y = __expf(s2y - mx);
      float ss = p0x + p0y + p1x + p1y + p2x + p2y;
#pragma unroll
      for (int off = 16; off > 0; off >>= 1) ss += __shfl_xor(ss, off, 32);
      inv[i] = 1.f / ss;
      const int rb = rbase + i * 152 + 2 * t;
      *(float2*)&ar[rb]      = make_float2(p0x, p0y);
      *(float2*)&ar[rb + 64] = make_float2(p1x, p1y);
      if (t <= 11) *(float2*)&ar[rb + 128] = make_float2(p2x, p2y);
    }

    float pv[5] = {0.f, 0.f, 0.f, 0.f, 0.f};
    for (int mq = 0; mq < 38; ++mq) {
      float4 vv = *(const float4*)&ar[BVB + t * 156 + 4 * mq];
#pragma unroll
      for (int i = 0; i < 5; ++i) {
        float4 pp = *(const float4*)&ar[rbase + i * 152 + 4 * mq];
        pv[i] += pp.x * vv.x + pp.y * vv.y + pp.z * vv.z + pp.w * vv.w;
      }
    }
#pragma unroll
    for (int i = 0; i < 5; ++i) ms += pv[i] * inv[i];
  }

  ar[BPART + g * 32 + t] = cfp + ms;
  __syncthreads();

  // ---- epilogue: mean over l, project with wo ----
  if (tid < 32) {
    float tot = 0.f;
#pragma unroll
    for (int gg = 0; gg < 8; ++gg) tot += ar[BPART + gg * 32 + tid];
    ar[BMS + tid] = tot * (1.f / 75.f);
  }
  __syncthreads();
  if (tid < 2) {
    float e = 0.f;
#pragma unroll
    for (int c2 = 0; c2 < CC; ++c2) e += wo[tid * CC + c2] * ar[BMS + c2];
    eout[a * 2 + tid] = e;
  }
}

// ---------------------------------------------------------------------------
// K5: meta head per site (unchanged)
// ---------------------------------------------------------------------------
__global__ __launch_bounds__(64) void k_meta(const float* __restrict__ cfs0,
                                             const float* __restrict__ cfa2,
                                             const float* __restrict__ mw,
                                             const float* __restrict__ mb,
                                             float* __restrict__ mout) {
  __shared__ float feat[64];
  __shared__ float lgt[3];
  const int s = blockIdx.x;
  const int tid = threadIdx.x;
  float f = 0.f;
  if (tid < 32) {
    const float* p = cfs0 + (size_t)s * (CC * LC) + tid * LC;
    for (int l = 0; l < LC; ++l) f += p[l];
  } else {
    const float* p0 = cfa2 + (size_t)(2 * s) * (CC * LC) + (tid - 32) * LC;
    const float* p1 = cfa2 + (size_t)(2 * s + 1) * (CC * LC) + (tid - 32) * LC;
    for (int l = 0; l < LC; ++l) f += p0[l] + p1[l];
  }
  feat[tid] = f * (1.f / 75.f);
  __syncthreads();
  if (tid < 3) {
    float acc2 = mb[tid];
    for (int c2 = 0; c2 < 64; ++c2) acc2 += mw[tid * 64 + c2] * feat[c2];
    lgt[tid] = acc2;
  }
  __syncthreads();
  if (tid < 3) {
    float mx = fmaxf(lgt[0], fmaxf(lgt[1], lgt[2]));
    float e0 = __expf(lgt[0] - mx), e1 = __expf(lgt[1] - mx), e2 = __expf(lgt[2] - mx);
    mout[s * 3 + tid] = __expf(lgt[tid] - mx) / (e0 + e1 + e2);
  }
}

// ---------------------------------------------------------------------------
extern "C" void kernel_launch(void* const* d_in, const int* in_sizes, int n_in,
                              void* d_out, int out_size, void* d_ws, size_t ws_size,
                              hipStream_t stream) {
  const float* t0      = (const float*)d_in[0];
  const float* t1      = (const float*)d_in[1];
  const float* conv0_w = (const float*)d_in[2];
  const float* conv1_w = (const float*)d_in[3];
  const float* comp0_w = (const float*)d_in[4];
  const float* comp1_w = (const float*)d_in[5];
  const float* comp2_w = (const float*)d_in[6];
  const float* xq0 = (const float*)d_in[7];
  const float* xk0 = (const float*)d_in[8];
  const float* xv0 = (const float*)d_in[9];
  const float* xo0 = (const float*)d_in[10];
  const float* xq1 = (const float*)d_in[11];
  const float* xk1 = (const float*)d_in[12];
  const float* xv1 = (const float*)d_in[13];
  const float* xo1 = (const float*)d_in[14];
  const float* xq2 = (const float*)d_in[15];
  const float* xk2 = (const float*)d_in[16];
  const float* xv2 = (const float*)d_in[17];
  const float* xo2 = (const float*)d_in[18];
  const float* comb_w = (const float*)d_in[19];
  const float* meta_w = (const float*)d_in[20];
  const float* meta_b = (const float*)d_in[21];

  float* wsf  = (float*)d_ws;
  float* red0 = wsf;
  float* red1 = red0 + (size_t)NA * CC * LL;
  float* cfa  = red1 + (size_t)NA * CC * LL;
  float* cfs0 = cfa + (size_t)NA * CC * LC;
  float* out  = (float*)d_out;

  k_conv_sum_mfma<<<NA, 256, 0, stream>>>(t0, conv0_w, red0);
  k_conv_sum_mfma<<<NA, 256, 0, stream>>>(t1, conv1_w, red1);

  k_compress2<<<NS, 256, 0, stream>>>(red0, comp0_w, cfa, cfs0);
  k_attn<<<NA, 256, 0, stream>>>(cfa, cfs0, xq0, xk0, xv0, xo0, out + 0);

  k_compress2<<<NS, 256, 0, stream>>>(red1, comp1_w, cfa, cfs0);
  k_attn<<<NA, 256, 0, stream>>>(cfa, cfs0, xq1, xk1, xv1, xo1, out + 2 * NA);

  k_comb<<<NA, 256, 0, stream>>>(red0, red1, comb_w, red0);
  k_compress2<<<NS, 256, 0, stream>>>(red0, comp2_w, cfa, cfs0);
  k_attn<<<NA, 256, 0, stream>>>(cfa, cfs0, xq2, xk2, xv2, xo2, out + 4 * NA);

  k_meta<<<NS, 64, 0, stream>>>(cfs0, cfa, meta_w, meta_b, out + 6 * NA);
}

// Round 7
// 1524.917 us; speedup vs baseline: 1.1260x; 1.1260x over previous
//
#include <hip/hip_runtime.h>
#include <math.h>

#define NS 1024
#define NA 2048
#define CIN 16
#define CC 32
#define LL 150
#define LC 75

typedef __attribute__((ext_vector_type(8))) short short8;
typedef __attribute__((ext_vector_type(4))) float float4v;

__device__ __forceinline__ unsigned short f2bf(float f) {
  // round-to-nearest-even fp32 -> bf16
  unsigned int u = __float_as_uint(f);
  unsigned int r = (u + 0x7FFFu + ((u >> 16) & 1u)) >> 16;
  return (unsigned short)r;
}

// ---------------------------------------------------------------------------
// K1 v3: conv1d(k=5,pad=2) + ReLU + sum over 16 reads, bf16 MFMA implicit GEMM.
// Double-buffered LDS staging (one barrier/stage) + PURE C++ f2bf conversion.
// (Round-6's inline-asm v_cvt_pk_bf16_f32 staging was -37%-class regression:
// asm blocks the compiler's load/convert/store scheduling — m240 effect.)
// LDS 2 x 9856 B. 256 threads.
// ---------------------------------------------------------------------------
__global__ __launch_bounds__(256) void k_conv_sum_mfma(const float* __restrict__ x,
                                                       const float* __restrict__ w,
                                                       float* __restrict__ red) {
  __shared__ unsigned short xs[2][154 * 32];   // 2 x 616 slots of 16B
  const int a = blockIdx.x;
  const int tid = threadIdx.x;
  const int lane = tid & 63;
  const int wv = tid >> 6;

  // A-fragments (weights) -> registers. lane holds A[m=lane&15][k=8*(lane>>4)+j]
  short8 afr[2][3];
  {
    const int mrow = lane & 15;
    const int h = lane >> 4;
    for (int mt = 0; mt < 2; ++mt) {
      const int c = mt * 16 + mrow;
      for (int s = 0; s < 3; ++s) {
        short8 f;
#pragma unroll
        for (int j = 0; j < 8; ++j) {
          int ic = 4 * h + (j >> 1);
          int tap = 2 * s + (j & 1);
          float wval = (tap < 5) ? w[c * 80 + ic * 5 + tap] : 0.f;
          f[j] = (short)f2bf(wval);
        }
        afr[mt][s] = f;
      }
    }
  }

  float4v sum[2][3];
#pragma unroll
  for (int mt = 0; mt < 2; ++mt)
#pragma unroll
    for (int nt = 0; nt < 3; ++nt) sum[mt][nt] = (float4v)(0.f);

  const int nbase = wv * 48;
  const int nrow = lane & 15;
  const int hh = lane >> 4;
  const float4v zf = (float4v)(0.f);

  // stage read r into buffer buf (all 616 slots fully written incl. pad rows)
  auto stage = [&](int r, int buf) {
    const float* xr = x + (size_t)(a * 16 + r) * (CIN * LL);
    for (int s = tid; s < 616; s += 256) {
      const int p = s >> 2;
      const int h4 = (s & 3) * 4;                  // ic base for this slot
      const float* xb = xr + h4 * LL + p;
      const bool qe_ok = (p >= 2) && (p <= 151);   // px[p]   = x[p-2]
      const bool qo_ok = (p >= 1) && (p <= 150);   // px[p+1] = x[p-1]
      short8 f;
#pragma unroll
      for (int c = 0; c < 4; ++c) {
        float ve = qe_ok ? xb[c * LL - 2] : 0.f;
        float vo = qo_ok ? xb[c * LL - 1] : 0.f;
        f[2 * c]     = (short)f2bf(ve);
        f[2 * c + 1] = (short)f2bf(vo);
      }
      *(short8*)&xs[buf][s * 8] = f;               // one conflict-free b128 write
    }
  };

  stage(0, 0);
  __syncthreads();

  for (int r = 0; r < 16; ++r) {
    const int cur = r & 1;
    if (r + 1 < 16) stage(r + 1, cur ^ 1);   // buf cur^1 last read pre-barrier — safe

    float4v acc[2][3];
#pragma unroll
    for (int s = 0; s < 3; ++s) {
#pragma unroll
      for (int nt = 0; nt < 3; ++nt) {
        int p = nbase + nt * 16 + nrow + 2 * s;
        if (p >= 154) p -= 154;                    // only for discarded cols
        short8 bfrag = *(const short8*)&xs[cur][(4 * p + hh) * 8];
#pragma unroll
        for (int mt = 0; mt < 2; ++mt) {
          acc[mt][nt] = __builtin_amdgcn_mfma_f32_16x16x32_bf16(
              afr[mt][s], bfrag, (s == 0) ? zf : acc[mt][nt], 0, 0, 0);
        }
      }
    }
#pragma unroll
    for (int mt = 0; mt < 2; ++mt)
#pragma unroll
      for (int nt = 0; nt < 3; ++nt)
#pragma unroll
        for (int q = 0; q < 4; ++q) sum[mt][nt][q] += fmaxf(acc[mt][nt][q], 0.f);

    __syncthreads();   // staging of r+1 done AND MFMA reads of r done
  }

  // C/D layout (16x16): col = lane&15 -> l, row = (lane>>4)*4+reg -> c
  const int ccol = lane & 15;
  const int crow4 = (lane >> 4) * 4;
  for (int mt = 0; mt < 2; ++mt)
    for (int nt = 0; nt < 3; ++nt) {
      int l = nbase + nt * 16 + ccol;
      if (l < LL) {
#pragma unroll
        for (int q = 0; q < 4; ++q) {
          int c = mt * 16 + crow4 + q;
          red[(size_t)a * (CC * LL) + c * LL + l] = sum[mt][nt][q];
        }
      }
    }
}

// ---------------------------------------------------------------------------
// K2: red2 = relu(comb_w @ [red0|red1]) in place over red0 (unchanged)
// ---------------------------------------------------------------------------
__global__ __launch_bounds__(256) void k_comb(const float* __restrict__ red0,
                                              const float* __restrict__ red1,
                                              const float* __restrict__ cw,
                                              float* __restrict__ out) {
  __shared__ float ins[64][152];
  __shared__ float cwl[64][CC];
  const int a = blockIdx.x;
  const int tid = threadIdx.x;

  for (int i = tid; i < 64 * CC; i += 256) {
    int c = i & 31; int c2 = i >> 5;
    cwl[c2][c] = cw[c * 64 + c2];
  }
  for (int i = tid; i < CC * LL; i += 256) {
    int c2 = i / LL; int l = i - c2 * LL;
    ins[c2][l] = red0[(size_t)a * (CC * LL) + i];
    ins[32 + c2][l] = red1[(size_t)a * (CC * LL) + i];
  }
  __syncthreads();

  const int c = tid & 31;
  const int lg = tid >> 5;
  const int l0 = lg * 19;
  const int nl = (LL - l0 < 19) ? (LL - l0) : 19;
  float v[19];
#pragma unroll
  for (int j = 0; j < 19; ++j) v[j] = 0.f;
  for (int c2 = 0; c2 < 64; ++c2) {
    float wv = cwl[c2][c];
#pragma unroll
    for (int j = 0; j < 19; ++j) v[j] += wv * ins[c2][l0 + j];
  }
  float* o = out + (size_t)a * (CC * LL) + c * LL + l0;
  for (int j = 0; j < nl; ++j) o[j] = fmaxf(v[j], 0.f);
}

// ---------------------------------------------------------------------------
// K3 v2: per-SITE fused compressor (unchanged from round 6).
// cfa0 = relu(v0), cfa1 = relu(v1), cfs = relu(v0+v1) in one pass.
// ---------------------------------------------------------------------------
__global__ __launch_bounds__(256) void k_compress2(const float* __restrict__ src,
                                                   const float* __restrict__ w,
                                                   float* __restrict__ cfa,
                                                   float* __restrict__ cfs) {
  __shared__ float ins0[CC][164];
  __shared__ float ins1[CC][164];
  __shared__ float ws[CC][3][CC];
  const int sfull = blockIdx.x;
  const int tid = threadIdx.x;

  for (int i = tid; i < CC * 3 * CC; i += 256) {
    int c = i & 31; int kk = i >> 5; int ic = kk / 3; int t = kk - ic * 3;
    ws[ic][t][c] = w[c * (CC * 3) + ic * 3 + t];
  }
  if (tid < CC) {
    ins0[tid][0] = 0.f; ins0[tid][1] = 0.f; ins0[tid][152] = 0.f; ins0[tid][153] = 0.f;
    ins1[tid][0] = 0.f; ins1[tid][1] = 0.f; ins1[tid][152] = 0.f; ins1[tid][153] = 0.f;
  }
  {
    const float* s0 = src + (size_t)(2 * sfull) * (CC * LL);
    const float* s1 = s0 + CC * LL;
    for (int i = tid; i < CC * LL; i += 256) {
      int ic = i / LL; int l = i - ic * LL;
      ins0[ic][l + 2] = s0[i];
      ins1[ic][l + 2] = s1[i];
    }
  }
  __syncthreads();

  const int c = tid & 31;
  const int jg = tid >> 5;
  const int j0 = jg * 10;
  const int nj = (LC - j0 < 10) ? (LC - j0) : 10;
  float v0[10], v1[10];
#pragma unroll
  for (int j = 0; j < 10; ++j) { v0[j] = 0.f; v1[j] = 0.f; }
  for (int ic = 0; ic < CC; ++ic) {
    float w0 = ws[ic][0][c], w1 = ws[ic][1][c], w2 = ws[ic][2][c];
    float xa[12], xb[12];
#pragma unroll
    for (int i = 0; i < 12; ++i) {
      xa[i] = ins0[ic][2 * j0 + 2 * i];
      xb[i] = ins1[ic][2 * j0 + 2 * i];
    }
#pragma unroll
    for (int j = 0; j < 10; ++j) {
      v0[j] += w0 * xa[j] + w1 * xa[j + 1] + w2 * xa[j + 2];
      v1[j] += w0 * xb[j] + w1 * xb[j + 1] + w2 * xb[j + 2];
    }
  }
  float* oa0 = cfa + (size_t)(2 * sfull) * (CC * LC) + c * LC + j0;
  float* oa1 = oa0 + CC * LC;
  float* os  = cfs + (size_t)sfull * (CC * LC) + c * LC + j0;
  for (int j = 0; j < nj; ++j) {
    float a0 = v0[j], a1 = v1[j];
    oa0[j] = fmaxf(a0, 0.f);
    oa1[j] = fmaxf(a1, 0.f);
    os[j]  = fmaxf(a0 + a1, 0.f);
  }
}

// ---------------------------------------------------------------------------
// K4 v5: per-ALLELE fused cross-attention, spill-free (unchanged from round 5)
// ---------------------------------------------------------------------------
#define BKV   0
#define BW    4800
#define BQT   8064
#define BCF   10464
#define BKB   10464
#define BVB   15328
#define BROWP 0
#define BPART 6080
#define BMS   6336
#define ARENA 20320

__global__ __launch_bounds__(256) void k_attn(const float* __restrict__ cfa,
                                              const float* __restrict__ cfs0,
                                              const float* __restrict__ wq,
                                              const float* __restrict__ wk,
                                              const float* __restrict__ wv,
                                              const float* __restrict__ wo,
                                              float* __restrict__ eout) {
  __shared__ float ar[ARENA];
  const int a = blockIdx.x;
  const int s = a >> 1;
  const int tid = threadIdx.x;
  const int g = tid >> 5;
  const int t = tid & 31;

  // ---- phase A: stage weights (in-major, stride 33), kv, cf ----
  for (int i = tid; i < CC * CC; i += 256) {
    int o = i >> 5, ii = i & 31;
    ar[BW + ii * 33 + o]        = wq[i];
    ar[BW + 1056 + ii * 33 + o] = wk[i];
    ar[BW + 2112 + ii * 33 + o] = wv[i];
  }
  {
    const float* sg = cfs0 + (size_t)s * (CC * LC);
    const float* a0 = cfa + (size_t)(2 * s) * (CC * LC);
    const float* a1 = a0 + CC * LC;
    const int sel = a & 1;
    for (int i = tid; i < CC * LC; i += 256) {
      int c = i / 75, l = i - c * 75;
      float v0 = a0[i], v1 = a1[i];
      ar[BKV + c * 150 + l]      = sg[i];
      ar[BKV + c * 150 + 75 + l] = v0 + v1;
      ar[BCF + c * 77 + l]       = sel ? v1 : v0;
    }
  }
  __syncthreads();

  // ---- phase B1: q -> QT (LDS), cf partial column-sum ----
  float cfp = 0.f;
  {
    float wqc[32];
#pragma unroll
    for (int ii = 0; ii < 32; ++ii) wqc[ii] = ar[BW + ii * 33 + t];
    for (int row = g; row < 75; row += 8) {
      float acc = 0.f;
#pragma unroll
      for (int ii = 0; ii < 32; ++ii) acc += wqc[ii] * ar[BCF + ii * 77 + row];
      ar[BQT + row * 32 + t] = acc;
      cfp += ar[BCF + t * 77 + row];
    }
  }
  __syncthreads();   // QT visible; CF reads done -> KB may overwrite

  // ---- phase B2: k,v projection -> KB (over CF), VB ----
  {
    float wkc[32], wvc[32];
#pragma unroll
    for (int ii = 0; ii < 32; ++ii) {
      wkc[ii] = ar[BW + 1056 + ii * 33 + t];
      wvc[ii] = ar[BW + 2112 + ii * 33 + t];
    }
    for (int idx = tid; idx < CC * LL; idx += 256) {
      int o = idx & 31, m = idx >> 5;
      float ka = 0.f, va = 0.f;
#pragma unroll
      for (int ii = 0; ii < 32; ++ii) {
        float x = ar[BKV + ii * 150 + m];
        ka += wkc[ii] * x;
        va += wvc[ii] * x;
      }
      ar[BKB + o * 152 + m] = ka;
      ar[BVB + o * 156 + m] = va;
    }
    if (tid < 64) ar[BVB + (tid >> 1) * 156 + 150 + (tid & 1)] = 0.f;  // PV pad
  }
  __syncthreads();   // KB/VB ready; KV+W dead -> ROWP may overwrite

  // ---- phase D: per-chunk (5 rows) scores -> softmax -> PV ----
  float ms = 0.f;
  const int rbase = BROWP + g * 760;
  const float scale = 0.17677669529663687f;   // 1/sqrt(32)
#pragma unroll 1
  for (int cc = 0; cc < 2; ++cc) {
    const int ch = g + 8 * cc;
    if (ch >= 15) break;
    const int r0 = ch * 5;

    float2 acc[5][3];
#pragma unroll
    for (int i = 0; i < 5; ++i)
#pragma unroll
      for (int u = 0; u < 3; ++u) acc[i][u] = make_float2(0.f, 0.f);

#pragma unroll 1
    for (int c2 = 0; c2 < 32; c2 += 2) {
      float2 q01[5];
#pragma unroll
      for (int i = 0; i < 5; ++i) q01[i] = *(const float2*)&ar[BQT + (r0 + i) * 32 + c2];
      const int cb0 = BKB + c2 * 152 + 2 * t;
      const int cb1 = cb0 + 152;
      float2 ka0 = *(const float2*)&ar[cb0];
      float2 ka1 = *(const float2*)&ar[cb0 + 64];
      float2 ka2 = *(const float2*)&ar[cb0 + 128];
      float2 kb0 = *(const float2*)&ar[cb1];
      float2 kb1 = *(const float2*)&ar[cb1 + 64];
      float2 kb2 = *(const float2*)&ar[cb1 + 128];
#pragma unroll
      for (int i = 0; i < 5; ++i) {
        acc[i][0].x += q01[i].x * ka0.x + q01[i].y * kb0.x;
        acc[i][0].y += q01[i].x * ka0.y + q01[i].y * kb0.y;
        acc[i][1].x += q01[i].x * ka1.x + q01[i].y * kb1.x;
        acc[i][1].y += q01[i].x * ka1.y + q01[i].y * kb1.y;
        acc[i][2].x += q01[i].x * ka2.x + q01[i].y * kb2.x;
        acc[i][2].y += q01[i].x * ka2.y + q01[i].y * kb2.y;
      }
    }

    float inv[5];
#pragma unroll
    for (int i = 0; i < 5; ++i) {
      float s0x = acc[i][0].x * scale, s0y = acc[i][0].y * scale;
      float s1x = acc[i][1].x * scale, s1y = acc[i][1].y * scale;
      float s2x = acc[i][2].x * scale, s2y = acc[i][2].y * scale;
      if (t >= 11) { s2x = -1e30f; s2y = -1e30f; }   // m=128+2t >= 150
      float mx = fmaxf(fmaxf(fmaxf(s0x, s0y), fmaxf(s1x, s1y)), fmaxf(s2x, s2y));
#pragma unroll
      for (int off = 16; off > 0; off >>= 1) mx = fmaxf(mx, __shfl_xor(mx, off, 32));
      float p0x = __expf(s0x - mx), p0y = __expf(s0y - mx);
      float p1x = __expf(s1x - mx), p1y = __expf(s1y - mx);
      float p2x = __expf(s2x - mx), p2y = __expf(s2y - mx);
      float ss = p0x + p0y + p1x + p1y + p2x + p2y;
#pragma unroll
      for (int off = 16; off > 0; off >>= 1) ss += __shfl_xor(ss, off, 32);
      inv[i] = 1.f / ss;
      const int rb = rbase + i * 152 + 2 * t;
      *(float2*)&ar[rb]      = make_float2(p0x, p0y);
      *(float2*)&ar[rb + 64] = make_float2(p1x, p1y);
      if (t <= 11) *(float2*)&ar[rb + 128] = make_float2(p2x, p2y);
    }

    float pv[5] = {0.f, 0.f, 0.f, 0.f, 0.f};
    for (int mq = 0; mq < 38; ++mq) {
      float4 vv = *(const float4*)&ar[BVB + t * 156 + 4 * mq];
#pragma unroll
      for (int i = 0; i < 5; ++i) {
        float4 pp = *(const float4*)&ar[rbase + i * 152 + 4 * mq];
        pv[i] += pp.x * vv.x + pp.y * vv.y + pp.z * vv.z + pp.w * vv.w;
      }
    }
#pragma unroll
    for (int i = 0; i < 5; ++i) ms += pv[i] * inv[i];
  }

  ar[BPART + g * 32 + t] = cfp + ms;
  __syncthreads();

  // ---- epilogue: mean over l, project with wo ----
  if (tid < 32) {
    float tot = 0.f;
#pragma unroll
    for (int gg = 0; gg < 8; ++gg) tot += ar[BPART + gg * 32 + tid];
    ar[BMS + tid] = tot * (1.f / 75.f);
  }
  __syncthreads();
  if (tid < 2) {
    float e = 0.f;
#pragma unroll
    for (int c2 = 0; c2 < CC; ++c2) e += wo[tid * CC + c2] * ar[BMS + c2];
    eout[a * 2 + tid] = e;
  }
}

// ---------------------------------------------------------------------------
// K5: meta head per site (unchanged)
// ---------------------------------------------------------------------------
__global__ __launch_bounds__(64) void k_meta(const float* __restrict__ cfs0,
                                             const float* __restrict__ cfa2,
                                             const float* __restrict__ mw,
                                             const float* __restrict__ mb,
                                             float* __restrict__ mout) {
  __shared__ float feat[64];
  __shared__ float lgt[3];
  const int s = blockIdx.x;
  const int tid = threadIdx.x;
  float f = 0.f;
  if (tid < 32) {
    const float* p = cfs0 + (size_t)s * (CC * LC) + tid * LC;
    for (int l = 0; l < LC; ++l) f += p[l];
  } else {
    const float* p0 = cfa2 + (size_t)(2 * s) * (CC * LC) + (tid - 32) * LC;
    const float* p1 = cfa2 + (size_t)(2 * s + 1) * (CC * LC) + (tid - 32) * LC;
    for (int l = 0; l < LC; ++l) f += p0[l] + p1[l];
  }
  feat[tid] = f * (1.f / 75.f);
  __syncthreads();
  if (tid < 3) {
    float acc2 = mb[tid];
    for (int c2 = 0; c2 < 64; ++c2) acc2 += mw[tid * 64 + c2] * feat[c2];
    lgt[tid] = acc2;
  }
  __syncthreads();
  if (tid < 3) {
    float mx = fmaxf(lgt[0], fmaxf(lgt[1], lgt[2]));
    float e0 = __expf(lgt[0] - mx), e1 = __expf(lgt[1] - mx), e2 = __expf(lgt[2] - mx);
    mout[s * 3 + tid] = __expf(lgt[tid] - mx) / (e0 + e1 + e2);
  }
}

// ---------------------------------------------------------------------------
extern "C" void kernel_launch(void* const* d_in, const int* in_sizes, int n_in,
                              void* d_out, int out_size, void* d_ws, size_t ws_size,
                              hipStream_t stream) {
  const float* t0      = (const float*)d_in[0];
  const float* t1      = (const float*)d_in[1];
  const float* conv0_w = (const float*)d_in[2];
  const float* conv1_w = (const float*)d_in[3];
  const float* comp0_w = (const float*)d_in[4];
  const float* comp1_w = (const float*)d_in[5];
  const float* comp2_w = (const float*)d_in[6];
  const float* xq0 = (const float*)d_in[7];
  const float* xk0 = (const float*)d_in[8];
  const float* xv0 = (const float*)d_in[9];
  const float* xo0 = (const float*)d_in[10];
  const float* xq1 = (const float*)d_in[11];
  const float* xk1 = (const float*)d_in[12];
  const float* xv1 = (const float*)d_in[13];
  const float* xo1 = (const float*)d_in[14];
  const float* xq2 = (const float*)d_in[15];
  const float* xk2 = (const float*)d_in[16];
  const float* xv2 = (const float*)d_in[17];
  const float* xo2 = (const float*)d_in[18];
  const float* comb_w = (const float*)d_in[19];
  const float* meta_w = (const float*)d_in[20];
  const float* meta_b = (const float*)d_in[21];

  float* wsf  = (float*)d_ws;
  float* red0 = wsf;
  float* red1 = red0 + (size_t)NA * CC * LL;
  float* cfa  = red1 + (size_t)NA * CC * LL;
  float* cfs0 = cfa + (size_t)NA * CC * LC;
  float* out  = (float*)d_out;

  k_conv_sum_mfma<<<NA, 256, 0, stream>>>(t0, conv0_w, red0);
  k_conv_sum_mfma<<<NA, 256, 0, stream>>>(t1, conv1_w, red1);

  k_compress2<<<NS, 256, 0, stream>>>(red0, comp0_w, cfa, cfs0);
  k_attn<<<NA, 256, 0, stream>>>(cfa, cfs0, xq0, xk0, xv0, xo0, out + 0);

  k_compress2<<<NS, 256, 0, stream>>>(red1, comp1_w, cfa, cfs0);
  k_attn<<<NA, 256, 0, stream>>>(cfa, cfs0, xq1, xk1, xv1, xo1, out + 2 * NA);

  k_comb<<<NA, 256, 0, stream>>>(red0, red1, comb_w, red0);
  k_compress2<<<NS, 256, 0, stream>>>(red0, comp2_w, cfa, cfs0);
  k_attn<<<NA, 256, 0, stream>>>(cfa, cfs0, xq2, xk2, xv2, xo2, out + 4 * NA);

  k_meta<<<NS, 64, 0, stream>>>(cfs0, cfa, meta_w, meta_b, out + 6 * NA);
}